// Round 1
// baseline (541.357 us; speedup 1.0000x reference)
//
#include <hip/hip_runtime.h>

// ShapeContext: weight is eye(NOUT) by construction (identity sparse-conv),
// so out[n, k*NIN + i] = (rules[k,n] < N ? features[rules[k,n], i] : 0) + bias[k*NIN+i].
// Pure gather -> memory-bound. One thread per float4 of output; 8 lanes per (k,n) pair.

#define N_SITES 131072   // 2^17
#define NIN 32
#define FV 27
#define NOUT 864         // FV * NIN

__global__ __launch_bounds__(256) void shape_context_gather(
    const float* __restrict__ features,   // [N, NIN]
    const float* __restrict__ bias,       // [NOUT]
    const int*   __restrict__ rules,      // [FV, N]
    float*       __restrict__ out)        // [N, NOUT]
{
    long long tid = (long long)blockIdx.x * blockDim.x + threadIdx.x;
    const long long total = (long long)FV * N_SITES * 8;  // float4s
    if (tid >= total) return;

    int       c = (int)(tid & 7);        // which float4 within the 32-ch row
    long long p = tid >> 3;              // pair index = k*N + n (rules order)
    int       k = (int)(p >> 17);        // N_SITES = 2^17
    int       n = (int)(p & (N_SITES - 1));

    int r = rules[p];

    float4 v;
    if (r >= 0 && r < N_SITES) {
        v = ((const float4*)(features + (long long)r * NIN))[c];
    } else {
        v = make_float4(0.f, 0.f, 0.f, 0.f);
    }

    const float4 b = ((const float4*)bias)[k * 8 + c];
    v.x += b.x; v.y += b.y; v.z += b.z; v.w += b.w;

    ((float4*)(out + (long long)n * NOUT + k * NIN))[c] = v;
}

extern "C" void kernel_launch(void* const* d_in, const int* in_sizes, int n_in,
                              void* d_out, int out_size, void* d_ws, size_t ws_size,
                              hipStream_t stream) {
    const float* features = (const float*)d_in[0];
    // d_in[1] = weight: eye(NOUT) by ShapeContext construction -> gather, not matmul
    const float* bias     = (const float*)d_in[2];
    const int*   rules    = (const int*)d_in[3];
    float*       out      = (float*)d_out;

    const long long total   = (long long)FV * N_SITES * 8;
    const int       threads = 256;
    const int       blocks  = (int)((total + threads - 1) / threads);

    shape_context_gather<<<blocks, threads, 0, stream>>>(features, bias, rules, out);
}

// Round 3
// 531.351 us; speedup vs baseline: 1.0188x; 1.0188x over previous
//
#include <hip/hip_runtime.h>

// ShapeContext: weight is eye(NOUT) by construction (identity sparse-conv),
// so out[n, k*NIN + i] = (rules[k,n] < N ? features[rules[k,n], i] : 0) + bias[k*NIN+i].
// Pure gather -> memory-bound.
//
// R3: nontemporal (streaming) stores for `out` + nontemporal loads for `rules`
// so the 453 MB write stream does not allocate in L2 and evict the 16.8 MB
// `features` working set. Uses clang ext_vector_type (native vector) because
// __builtin_nontemporal_* rejects HIP's struct-based float4.

#define N_SITES 131072   // 2^17
#define NIN 32
#define FV 27
#define NOUT 864         // FV * NIN

typedef float f32x4 __attribute__((ext_vector_type(4)));

__global__ __launch_bounds__(256) void shape_context_gather(
    const float* __restrict__ features,   // [N, NIN]
    const float* __restrict__ bias,       // [NOUT]
    const int*   __restrict__ rules,      // [FV, N]
    float*       __restrict__ out)        // [N, NOUT]
{
    long long tid = (long long)blockIdx.x * blockDim.x + threadIdx.x;
    const long long total = (long long)FV * N_SITES * 8;  // float4s
    if (tid >= total) return;

    int       c = (int)(tid & 7);        // which float4 within the 32-ch row
    long long p = tid >> 3;              // pair index = k*N + n (rules order)
    int       k = (int)(p >> 17);        // N_SITES = 2^17
    int       n = (int)(p & (N_SITES - 1));

    int r = __builtin_nontemporal_load(rules + p);   // streamed once, no reuse

    bool valid = (r >= 0) && (r < N_SITES);
    int rr = valid ? r : 0;              // branch-free: clamp then mask
    f32x4 v = ((const f32x4*)(features + (long long)rr * NIN))[c];
    if (!valid) v = (f32x4){0.f, 0.f, 0.f, 0.f};

    const f32x4 b = ((const f32x4*)bias)[k * 8 + c];
    v += b;

    f32x4* dst = (f32x4*)(out + (long long)n * NOUT + k * NIN) + c;
    __builtin_nontemporal_store(v, dst);   // streaming store: don't pollute L2
}

extern "C" void kernel_launch(void* const* d_in, const int* in_sizes, int n_in,
                              void* d_out, int out_size, void* d_ws, size_t ws_size,
                              hipStream_t stream) {
    const float* features = (const float*)d_in[0];
    // d_in[1] = weight: eye(NOUT) by ShapeContext construction -> gather, not matmul
    const float* bias     = (const float*)d_in[2];
    const int*   rules    = (const int*)d_in[3];
    float*       out      = (float*)d_out;

    const long long total   = (long long)FV * N_SITES * 8;
    const int       threads = 256;
    const int       blocks  = (int)((total + threads - 1) / threads);

    shape_context_gather<<<blocks, threads, 0, stream>>>(features, bias, rules, out);
}